// Round 3
// baseline (504.238 us; speedup 1.0000x reference)
//
#include <hip/hip_runtime.h>
#include <cstdint>

// ---------- types ----------
typedef __bf16 bf16x8 __attribute__((ext_vector_type(8)));
typedef float  f32x4  __attribute__((ext_vector_type(4)));

// Problem constants: BATCH=8, N_SEQS=4, SEQ_LEN=2048, D=512 -> 32 seqs, 65536 rows
#define SEQS   32
#define SLEN   2048
#define DIM    512
#define MROWS  65536

static __device__ __forceinline__ void load_lds16(const void* g, void* l) {
  __builtin_amdgcn_global_load_lds(
      (const __attribute__((address_space(1))) void*)(uintptr_t)g,
      (__attribute__((address_space(3))) void*)(uintptr_t)l,
      16, 0, 0);
}

static __device__ __forceinline__ unsigned short bfbits(float f) {
  __bf16 h = (__bf16)f;
  unsigned short u;
  __builtin_memcpy(&u, &h, 2);
  return u;
}

// ---------- BT-GEMM core, 128x128 tile, BK=64, 256 threads (4 waves 2x2) ----------
// C[m,n] += sum_k A[m,k]*B[n,k]. LDS tiles [128][64] bf16 (128B rows, 8x16B slots),
// XOR-swizzled (slot ^ (row&7)); swizzle applied to the global SOURCE address
// (linear LDS dest via global_load_lds) and to the ds_read offsets. 0 conflicts
// (verified round 2).
static __device__ __forceinline__ void gemm_core(
    const __bf16* __restrict__ A, int lda, int arow0,
    const __bf16* __restrict__ B, int ldb, int brow0,
    int K, __bf16* Asm, __bf16* Bsm, f32x4 (&acc)[4][4])
{
  const int tid  = threadIdx.x;
  const int wave = tid >> 6;
  const int lane = tid & 63;
  const int wr = wave >> 1, wc = wave & 1;
  const int lr = lane & 15, kq = lane >> 4;

  for (int kt = 0; kt < K; kt += 64) {
#pragma unroll
    for (int q = 0; q < 4; ++q) {
      const int L  = q * 4096 + tid * 16;   // linear byte in 16KB region
      const int r  = L >> 7;                // 128B per row
      const int sl = (L >> 4) & 7;          // 16B slot in row
      const int c  = ((sl ^ (r & 7)) << 3); // swizzled element col
      load_lds16(A + (size_t)(arow0 + r) * lda + (kt + c),
                 (char*)Asm + q * 4096 + wave * 1024);
      load_lds16(B + (size_t)(brow0 + r) * ldb + (kt + c),
                 (char*)Bsm + q * 4096 + wave * 1024);
    }
    __syncthreads();

    bf16x8 af[2][4], bfr[2][4];
#pragma unroll
    for (int kk = 0; kk < 2; ++kk)
#pragma unroll
      for (int i = 0; i < 4; ++i) {
        const int rA = wr * 64 + i * 16 + lr;
        af[kk][i] = *reinterpret_cast<const bf16x8*>(
            (char*)Asm + rA * 128 + ((((kk * 4 + kq) ^ (rA & 7))) << 4));
        const int rB = wc * 64 + i * 16 + lr;
        bfr[kk][i] = *reinterpret_cast<const bf16x8*>(
            (char*)Bsm + rB * 128 + ((((kk * 4 + kq) ^ (rB & 7))) << 4));
      }
#pragma unroll
    for (int kk = 0; kk < 2; ++kk)
#pragma unroll
      for (int i = 0; i < 4; ++i)
#pragma unroll
        for (int j = 0; j < 4; ++j)
          acc[i][j] = __builtin_amdgcn_mfma_f32_16x16x32_bf16(
              af[kk][i], bfr[kk][j], acc[i][j], 0, 0, 0);
    __syncthreads();
  }
}

// ---------- kernels ----------

__global__ __launch_bounds__(256) void cast_kernel(
    const float* __restrict__ src, __bf16* __restrict__ dst, int n8)
{
  int i = blockIdx.x * blockDim.x + threadIdx.x;
  const int stride = gridDim.x * blockDim.x;
  for (; i < n8; i += stride) {
    const float4* p = reinterpret_cast<const float4*>(src + (size_t)i * 8);
    float4 a = p[0], b2 = p[1];
    float vals[8] = {a.x, a.y, a.z, a.w, b2.x, b2.y, b2.z, b2.w};
    uint32_t w[4];
#pragma unroll
    for (int t = 0; t < 4; ++t)
      w[t] = (uint32_t)bfbits(vals[2 * t]) | ((uint32_t)bfbits(vals[2 * t + 1]) << 16);
    uint4 o; o.x = w[0]; o.y = w[1]; o.z = w[2]; o.w = w[3];
    *reinterpret_cast<uint4*>(dst + (size_t)i * 8) = o;
  }
}

// 4 weight matrices (512x512 each) in one dispatch, grid (128,4)
__global__ __launch_bounds__(256) void cast4_kernel(
    const float* __restrict__ a, const float* __restrict__ b,
    const float* __restrict__ c, const float* __restrict__ d,
    __bf16* __restrict__ ab, __bf16* __restrict__ bb,
    __bf16* __restrict__ cb, __bf16* __restrict__ db)
{
  const int z = blockIdx.y;
  const float* src = (z == 0) ? a : (z == 1) ? b : (z == 2) ? c : d;
  __bf16* dst = (z == 0) ? ab : (z == 1) ? bb : (z == 2) ? cb : db;
  const int i = blockIdx.x * 256 + threadIdx.x;   // < 32768
  const float4* p = reinterpret_cast<const float4*>(src + (size_t)i * 8);
  float4 x = p[0], y = p[1];
  float vals[8] = {x.x, x.y, x.z, x.w, y.x, y.y, y.z, y.w};
  uint32_t w[4];
#pragma unroll
  for (int t = 0; t < 4; ++t)
    w[t] = (uint32_t)bfbits(vals[2 * t]) | ((uint32_t)bfbits(vals[2 * t + 1]) << 16);
  uint4 o; o.x = w[0]; o.y = w[1]; o.z = w[2]; o.w = w[3];
  *reinterpret_cast<uint4*>(dst + (size_t)i * 8) = o;
}

// QKV projection: 6144 blocks, XCD-pinned: all 12 consumers (z,bcol) of one
// x-panel (brow) land on XCD brow%8, adjacent in dispatch order.
// z=0 -> Q (phi), z=1 -> K^T (phi) + ksum atomics, z=2 -> V^T
__global__ __launch_bounds__(256) void qkv_kernel(
    const __bf16* __restrict__ xb,
    const __bf16* __restrict__ Wqb, const __bf16* __restrict__ Wkb,
    const __bf16* __restrict__ Wvb,
    __bf16* __restrict__ Q, __bf16* __restrict__ KT, __bf16* __restrict__ VT,
    float* __restrict__ ksum)
{
  __shared__ __align__(16) __bf16 Asm[128 * 64];
  __shared__ __align__(16) __bf16 Bsm[128 * 64];
  const int b = blockIdx.x;
  const int xcd = b & 7, loc = b >> 3;
  const int brow = (loc / 12) * 8 + xcd;          // 512 panels, pinned per XCD
  const int bx = loc % 12;
  const int z = bx >> 2, bcol = bx & 3;
  const __bf16* W = (z == 0) ? Wqb : (z == 1) ? Wkb : Wvb;
  f32x4 acc[4][4] = {};
  gemm_core(xb, DIM, brow * 128, W, DIM, bcol * 128, DIM, Asm, Bsm, acc);

  const int tid = threadIdx.x, wave = tid >> 6, lane = tid & 63;
  const int wr = wave >> 1, wc = wave & 1, lr = lane & 15, kq = lane >> 4;
  const int m0 = brow * 128 + wr * 64 + kq * 4;
  const int n0 = bcol * 128 + wc * 64 + lr;

  if (z == 0) {
#pragma unroll
    for (int i = 0; i < 4; ++i)
#pragma unroll
      for (int j = 0; j < 4; ++j) {
        const int n = n0 + j * 16;
#pragma unroll
        for (int r = 0; r < 4; ++r) {
          const int m = m0 + i * 16 + r;
          float v = acc[i][j][r];
          v = (v > 0.f) ? (v + 1.f) : __expf(v);   // elu(v)+1
          Q[(size_t)m * DIM + n] = (__bf16)v;
        }
      }
  } else {
    __bf16* T = (z == 1) ? KT : VT;
    const int seq = (brow * 128) >> 11;
    float ks[4] = {0.f, 0.f, 0.f, 0.f};
#pragma unroll
    for (int i = 0; i < 4; ++i) {
      const int mb = m0 + i * 16;
      const int s0 = mb & 2047;
#pragma unroll
      for (int j = 0; j < 4; ++j) {
        const int d = n0 + j * 16;
        unsigned short h[4];
#pragma unroll
        for (int r = 0; r < 4; ++r) {
          float v = acc[i][j][r];
          if (z == 1) { v = (v > 0.f) ? (v + 1.f) : __expf(v); ks[j] += v; }
          h[r] = bfbits(v);
        }
        uint2 u;
        u.x = (uint32_t)h[0] | ((uint32_t)h[1] << 16);
        u.y = (uint32_t)h[2] | ((uint32_t)h[3] << 16);
        *reinterpret_cast<uint2*>(T + ((size_t)(seq * DIM + d) << 11) + s0) = u;
      }
    }
    if (z == 1) {
#pragma unroll
      for (int j = 0; j < 4; ++j) {
        float p = ks[j];
        p += __shfl_xor(p, 16, 64);
        p += __shfl_xor(p, 32, 64);
        if (kq == 0) atomicAdd(&ksum[seq * DIM + n0 + j * 16], p);
      }
    }
  }
}

// kvT[seq][e][d] = sum_s VT[seq][e][s] * KT[seq][d][s]; 512 blocks, each seq's
// 16 blocks pinned to XCD seq%8 (KT/VT panels fetched once per seq).
__global__ __launch_bounds__(256) void kv_kernel(
    const __bf16* __restrict__ VT, const __bf16* __restrict__ KT,
    __bf16* __restrict__ kvT)
{
  __shared__ __align__(16) __bf16 Asm[128 * 64];
  __shared__ __align__(16) __bf16 Bsm[128 * 64];
  const int b = blockIdx.x;
  const int xcd = b & 7, loc = b >> 3;
  const int seq = (loc >> 4) * 8 + xcd;
  const int inner = loc & 15;
  const int bxx = inner >> 2, byy = inner & 3;
  const __bf16* A = VT + (size_t)seq * DIM * SLEN;
  const __bf16* B = KT + (size_t)seq * DIM * SLEN;
  f32x4 acc[4][4] = {};
  gemm_core(A, SLEN, bxx * 128, B, SLEN, byy * 128, SLEN, Asm, Bsm, acc);

  const int tid = threadIdx.x, wave = tid >> 6, lane = tid & 63;
  const int wr = wave >> 1, wc = wave & 1, lr = lane & 15, kq = lane >> 4;
  const int m0 = bxx * 128 + wr * 64 + kq * 4;
  const int n0 = byy * 128 + wc * 64 + lr;
  __bf16* C = kvT + (size_t)seq * DIM * DIM;
#pragma unroll
  for (int i = 0; i < 4; ++i)
#pragma unroll
    for (int j = 0; j < 4; ++j)
#pragma unroll
      for (int r = 0; r < 4; ++r)
        C[(size_t)(m0 + i * 16 + r) * DIM + (n0 + j * 16)] = (__bf16)acc[i][j][r];
}

// out[m,e] = (sum_d Q[m,d]*kvT[seq][e][d]) / den[m]; den fused (pre-pass).
// 2048 blocks; each seq's 64 blocks (16 brow x 4 bcol) pinned to XCD seq%8.
__global__ __launch_bounds__(256) void num_kernel(
    const __bf16* __restrict__ Q, const __bf16* __restrict__ kvT,
    const float* __restrict__ ksum, __bf16* __restrict__ out)
{
  __shared__ __align__(16) __bf16 Asm[128 * 64];
  __shared__ __align__(16) __bf16 Bsm[128 * 64];
  __shared__ float denL[128];
  const int b = blockIdx.x;
  const int xcd = b & 7, loc = b >> 3;
  const int seq = (loc >> 6) * 8 + xcd;
  const int inner = loc & 63;
  const int brow = seq * 16 + (inner >> 2);
  const int bcol = inner & 3;
  const int tid = threadIdx.x;

  // den pre-pass: thread t -> row t/2, half t&1 (256 cols)
  {
    const int row = tid >> 1, h = tid & 1;
    const __bf16* qr = Q + (size_t)(brow * 128 + row) * DIM + h * 256;
    const float* kr = ksum + seq * DIM + h * 256;
    float s = 0.f;
#pragma unroll
    for (int c = 0; c < 256; c += 8) {
      bf16x8 qv = *reinterpret_cast<const bf16x8*>(qr + c);
      float4 k0 = *reinterpret_cast<const float4*>(kr + c);
      float4 k1 = *reinterpret_cast<const float4*>(kr + c + 4);
      s += (float)qv[0] * k0.x + (float)qv[1] * k0.y +
           (float)qv[2] * k0.z + (float)qv[3] * k0.w +
           (float)qv[4] * k1.x + (float)qv[5] * k1.y +
           (float)qv[6] * k1.z + (float)qv[7] * k1.w;
    }
    s += __shfl_xor(s, 1, 64);
    if (h == 0) denL[row] = fmaxf(s, 1e-6f);
  }
  __syncthreads();

  f32x4 acc[4][4] = {};
  gemm_core(Q, DIM, brow * 128, kvT + (size_t)seq * DIM * DIM, DIM,
            bcol * 128, DIM, Asm, Bsm, acc);

  const int wave = tid >> 6, lane = tid & 63;
  const int wr = wave >> 1, wc = wave & 1, lr = lane & 15, kq = lane >> 4;
  const int ml0 = wr * 64 + kq * 4;
  const int m0 = brow * 128 + ml0;
  const int n0 = bcol * 128 + wc * 64 + lr;
  float rden[4][4];
#pragma unroll
  for (int i = 0; i < 4; ++i)
#pragma unroll
    for (int r = 0; r < 4; ++r)
      rden[i][r] = 1.f / denL[ml0 + i * 16 + r];
#pragma unroll
  for (int i = 0; i < 4; ++i)
#pragma unroll
    for (int j = 0; j < 4; ++j)
#pragma unroll
      for (int r = 0; r < 4; ++r)
        out[(size_t)(m0 + i * 16 + r) * DIM + (n0 + j * 16)] =
            (__bf16)(acc[i][j][r] * rden[i][r]);
}

// Fused out-proj + bias + residual + LayerNorm. One block = 128 rows x 512 cols,
// 1024 threads (16 waves, 4x4): per-lane acc[2][8] = 64 f32 -> fits in 128 VGPR
// (round-2's 512t/acc[2][16]=128f32 spilled: VGPR_Count 128 < need ~190 ->
// MfmaUtil 0.6%). LDS: A [128][32] 8KB + B [512][32] 32KB + red 4KB = 44KB,
// 2 blocks/CU = 32 waves. Swizzle for 64B rows: slot ^= (row>>1)&3 -> 2-way free.
__global__ __launch_bounds__(1024, 4) void final_kernel(
    const __bf16* __restrict__ outb, const __bf16* __restrict__ Wob,
    const float* __restrict__ bo, const float* __restrict__ gamma,
    const float* __restrict__ beta, float* __restrict__ y)
{
  __shared__ __align__(16) __bf16 Asm[128 * 32];
  __shared__ __align__(16) __bf16 Bsm[512 * 32];
  __shared__ float redS[4][128], redSS[4][128];
  const int tid = threadIdx.x, wave = tid >> 6, lane = tid & 63;
  const int Wr = wave >> 2, Wc = wave & 3;       // 4x4 waves: 32 rows x 128 cols
  const int lr = lane & 15, kq = lane >> 4;
  const int brow = blockIdx.x;
  f32x4 acc[2][8] = {};

  for (int kt = 0; kt < DIM; kt += 32) {
    if (wave < 8) {                               // A: 8KB, waves 0-7
      const int L = tid * 16;
      const int r = L >> 6, sl = (L >> 4) & 3;
      const int c = ((sl ^ ((r >> 1) & 3)) << 3);
      load_lds16(outb + (size_t)(brow * 128 + r) * DIM + (kt + c),
                 (char*)Asm + wave * 1024);
    }
#pragma unroll
    for (int q = 0; q < 2; ++q) {                 // B: 32KB, all waves x2
      const int L = q * 16384 + tid * 16;
      const int r = L >> 6, sl = (L >> 4) & 3;
      const int c = ((sl ^ ((r >> 1) & 3)) << 3);
      load_lds16(Wob + (size_t)r * DIM + (kt + c),
                 (char*)Bsm + q * 16384 + wave * 1024);
    }
    __syncthreads();
    bf16x8 af[2];
#pragma unroll
    for (int i = 0; i < 2; ++i) {
      const int rA = Wr * 32 + i * 16 + lr;
      af[i] = *reinterpret_cast<const bf16x8*>(
          (char*)Asm + rA * 64 + ((kq ^ ((rA >> 1) & 3)) << 4));
    }
#pragma unroll
    for (int j = 0; j < 8; ++j) {
      const int rB = Wc * 128 + j * 16 + lr;
      bf16x8 bf = *reinterpret_cast<const bf16x8*>(
          (char*)Bsm + rB * 64 + ((kq ^ ((rB >> 1) & 3)) << 4));
#pragma unroll
      for (int i = 0; i < 2; ++i)
        acc[i][j] = __builtin_amdgcn_mfma_f32_16x16x32_bf16(af[i], bf, acc[i][j], 0, 0, 0);
    }
    __syncthreads();
  }

  // epilogue: v = acc + bo + residual; LN over 512 cols per row
  const int m0g = brow * 128;
  float sA[2][4] = {{0.f}}, ssA[2][4] = {{0.f}};
#pragma unroll
  for (int j = 0; j < 8; ++j) {
    const int n = Wc * 128 + j * 16 + lr;
    const float bon = bo[n];
#pragma unroll
    for (int i = 0; i < 2; ++i) {
      const int mb = m0g + Wr * 32 + i * 16 + kq * 4;
#pragma unroll
      for (int r = 0; r < 4; ++r) {
        float v = acc[i][j][r] + bon + (float)outb[(size_t)(mb + r) * DIM + n];
        acc[i][j][r] = v;
        sA[i][r] += v; ssA[i][r] += v * v;
      }
    }
  }
#pragma unroll
  for (int i = 0; i < 2; ++i)
#pragma unroll
    for (int r = 0; r < 4; ++r) {
      float s = sA[i][r], ss = ssA[i][r];
#pragma unroll
      for (int off = 1; off <= 8; off <<= 1) {
        s  += __shfl_xor(s,  off, 64);
        ss += __shfl_xor(ss, off, 64);
      }
      if (lr == 0) {
        const int ml = Wr * 32 + i * 16 + kq * 4 + r;
        redS[Wc][ml] = s; redSS[Wc][ml] = ss;
      }
    }
  __syncthreads();
  float mu_[2][4], rs_[2][4];
#pragma unroll
  for (int i = 0; i < 2; ++i)
#pragma unroll
    for (int r = 0; r < 4; ++r) {
      const int ml = Wr * 32 + i * 16 + kq * 4 + r;
      const float S  = redS[0][ml] + redS[1][ml] + redS[2][ml] + redS[3][ml];
      const float SS = redSS[0][ml] + redSS[1][ml] + redSS[2][ml] + redSS[3][ml];
      const float mu = S * (1.f / 512.f);
      const float var = SS * (1.f / 512.f) - mu * mu;
      mu_[i][r] = mu;
      rs_[i][r] = rsqrtf(var + 1e-5f);
    }
#pragma unroll
  for (int j = 0; j < 8; ++j) {
    const int n = Wc * 128 + j * 16 + lr;
    const float g = gamma[n], bb = beta[n];
#pragma unroll
    for (int i = 0; i < 2; ++i) {
      const int mb = m0g + Wr * 32 + i * 16 + kq * 4;
#pragma unroll
      for (int r = 0; r < 4; ++r)
        y[(size_t)(mb + r) * DIM + n] = (acc[i][j][r] - mu_[i][r]) * rs_[i][r] * g + bb;
    }
  }
}

// ---------- launch ----------
extern "C" void kernel_launch(void* const* d_in, const int* in_sizes, int n_in,
                              void* d_out, int out_size, void* d_ws, size_t ws_size,
                              hipStream_t stream)
{
  const float* x     = (const float*)d_in[0];
  const float* Wq    = (const float*)d_in[1];
  const float* Wk    = (const float*)d_in[2];
  const float* Wv    = (const float*)d_in[3];
  const float* Wo    = (const float*)d_in[4];
  const float* bo    = (const float*)d_in[5];
  const float* gamma = (const float*)d_in[6];
  const float* beta  = (const float*)d_in[7];
  float* outp = (float*)d_out;

  char* ws = (char*)d_ws;
  const size_t SZ = 67108864;                      // 64 MiB (bf16 [65536][512])
  __bf16* xb   = (__bf16*)(ws + 0);                // reused as `out` after qkv
  __bf16* Q    = (__bf16*)(ws + SZ);
  __bf16* KT   = (__bf16*)(ws + 2 * SZ);
  __bf16* VT   = (__bf16*)(ws + 3 * SZ);
  __bf16* kvT  = (__bf16*)(ws + 4 * SZ);           // 16 MiB
  __bf16* Wqb  = (__bf16*)(ws + 4 * SZ + 16777216);
  __bf16* Wkb  = Wqb + 262144;
  __bf16* Wvb  = Wkb + 262144;
  __bf16* Wob  = Wvb + 262144;
  float*  ksum = (float*)(Wob + 262144);           // 32*512 f32 = 64 KiB

  hipMemsetAsync(ksum, 0, SEQS * DIM * sizeof(float), stream);
  cast_kernel<<<4096, 256, 0, stream>>>(x, xb, MROWS * DIM / 8);
  cast4_kernel<<<dim3(128, 4), 256, 0, stream>>>(Wq, Wk, Wv, Wo, Wqb, Wkb, Wvb, Wob);

  qkv_kernel<<<6144, 256, 0, stream>>>(xb, Wqb, Wkb, Wvb, Q, KT, VT, ksum);
  kv_kernel<<<512, 256, 0, stream>>>(VT, KT, kvT);
  num_kernel<<<2048, 256, 0, stream>>>(Q, kvT, ksum, xb /*out*/);
  final_kernel<<<512, 1024, 0, stream>>>(xb, Wob, bo, gamma, beta, outp);
}

// Round 4
// 423.975 us; speedup vs baseline: 1.1893x; 1.1893x over previous
//
#include <hip/hip_runtime.h>
#include <cstdint>

// ---------- types ----------
typedef __bf16 bf16x8 __attribute__((ext_vector_type(8)));
typedef float  f32x4  __attribute__((ext_vector_type(4)));

// Problem constants: BATCH=8, N_SEQS=4, SEQ_LEN=2048, D=512 -> 32 seqs, 65536 rows
#define SEQS   32
#define SLEN   2048
#define DIM    512
#define MROWS  65536

static __device__ __forceinline__ void load_lds16(const void* g, void* l) {
  __builtin_amdgcn_global_load_lds(
      (const __attribute__((address_space(1))) void*)(uintptr_t)g,
      (__attribute__((address_space(3))) void*)(uintptr_t)l,
      16, 0, 0);
}

static __device__ __forceinline__ unsigned short bfbits(float f) {
  __bf16 h = (__bf16)f;
  unsigned short u;
  __builtin_memcpy(&u, &h, 2);
  return u;
}

// ---------- BT-GEMM core, 128x128 tile, BK=64, 256 threads (4 waves 2x2) ----------
// (kept for kv/num; 0 LDS bank conflicts verified in round 2)
static __device__ __forceinline__ void gemm_core(
    const __bf16* __restrict__ A, int lda, int arow0,
    const __bf16* __restrict__ B, int ldb, int brow0,
    int K, __bf16* Asm, __bf16* Bsm, f32x4 (&acc)[4][4])
{
  const int tid  = threadIdx.x;
  const int wave = tid >> 6;
  const int lane = tid & 63;
  const int wr = wave >> 1, wc = wave & 1;
  const int lr = lane & 15, kq = lane >> 4;

  for (int kt = 0; kt < K; kt += 64) {
#pragma unroll
    for (int q = 0; q < 4; ++q) {
      const int L  = q * 4096 + tid * 16;
      const int r  = L >> 7;
      const int sl = (L >> 4) & 7;
      const int c  = ((sl ^ (r & 7)) << 3);
      load_lds16(A + (size_t)(arow0 + r) * lda + (kt + c),
                 (char*)Asm + q * 4096 + wave * 1024);
      load_lds16(B + (size_t)(brow0 + r) * ldb + (kt + c),
                 (char*)Bsm + q * 4096 + wave * 1024);
    }
    __syncthreads();

    bf16x8 af[2][4], bfr[2][4];
#pragma unroll
    for (int kk = 0; kk < 2; ++kk)
#pragma unroll
      for (int i = 0; i < 4; ++i) {
        const int rA = wr * 64 + i * 16 + lr;
        af[kk][i] = *reinterpret_cast<const bf16x8*>(
            (char*)Asm + rA * 128 + ((((kk * 4 + kq) ^ (rA & 7))) << 4));
        const int rB = wc * 64 + i * 16 + lr;
        bfr[kk][i] = *reinterpret_cast<const bf16x8*>(
            (char*)Bsm + rB * 128 + ((((kk * 4 + kq) ^ (rB & 7))) << 4));
      }
#pragma unroll
    for (int kk = 0; kk < 2; ++kk)
#pragma unroll
      for (int i = 0; i < 4; ++i)
#pragma unroll
        for (int j = 0; j < 4; ++j)
          acc[i][j] = __builtin_amdgcn_mfma_f32_16x16x32_bf16(
              af[kk][i], bfr[kk][j], acc[i][j], 0, 0, 0);
    __syncthreads();
  }
}

// ---------- kernels ----------

__global__ __launch_bounds__(256) void cast_kernel(
    const float* __restrict__ src, __bf16* __restrict__ dst, int n8)
{
  int i = blockIdx.x * blockDim.x + threadIdx.x;
  const int stride = gridDim.x * blockDim.x;
  for (; i < n8; i += stride) {
    const float4* p = reinterpret_cast<const float4*>(src + (size_t)i * 8);
    float4 a = p[0], b2 = p[1];
    float vals[8] = {a.x, a.y, a.z, a.w, b2.x, b2.y, b2.z, b2.w};
    uint32_t w[4];
#pragma unroll
    for (int t = 0; t < 4; ++t)
      w[t] = (uint32_t)bfbits(vals[2 * t]) | ((uint32_t)bfbits(vals[2 * t + 1]) << 16);
    uint4 o; o.x = w[0]; o.y = w[1]; o.z = w[2]; o.w = w[3];
    *reinterpret_cast<uint4*>(dst + (size_t)i * 8) = o;
  }
}

__global__ __launch_bounds__(256) void cast4_kernel(
    const float* __restrict__ a, const float* __restrict__ b,
    const float* __restrict__ c, const float* __restrict__ d,
    __bf16* __restrict__ ab, __bf16* __restrict__ bb,
    __bf16* __restrict__ cb, __bf16* __restrict__ db)
{
  const int z = blockIdx.y;
  const float* src = (z == 0) ? a : (z == 1) ? b : (z == 2) ? c : d;
  __bf16* dst = (z == 0) ? ab : (z == 1) ? bb : (z == 2) ? cb : db;
  const int i = blockIdx.x * 256 + threadIdx.x;
  const float4* p = reinterpret_cast<const float4*>(src + (size_t)i * 8);
  float4 x = p[0], y = p[1];
  float vals[8] = {x.x, x.y, x.z, x.w, y.x, y.y, y.z, y.w};
  uint32_t w[4];
#pragma unroll
  for (int t = 0; t < 4; ++t)
    w[t] = (uint32_t)bfbits(vals[2 * t]) | ((uint32_t)bfbits(vals[2 * t + 1]) << 16);
  uint4 o; o.x = w[0]; o.y = w[1]; o.z = w[2]; o.w = w[3];
  *reinterpret_cast<uint4*>(dst + (size_t)i * 8) = o;
}

// QKV projection: 256x256 tile, 512 threads (8 waves 2Mx4N), BK=32,
// double-buffered LDS (64KB), ONE barrier per K-tile (T3-minimum 2-phase:
// next-tile global_load_lds issued BEFORE compute; __syncthreads' vmcnt(0)
// drain is the fence). 1536 blocks XCD-pinned: the 6 consumers (z,bcol) of
// each 256-row x-panel land on XCD brow%8.
__global__ __launch_bounds__(512, 1) void qkv_kernel(
    const __bf16* __restrict__ xb,
    const __bf16* __restrict__ Wqb, const __bf16* __restrict__ Wkb,
    const __bf16* __restrict__ Wvb,
    __bf16* __restrict__ Q, __bf16* __restrict__ KT, __bf16* __restrict__ VT,
    float* __restrict__ ksum)
{
  __shared__ __align__(16) __bf16 As[2][256 * 32];   // 16KB x2
  __shared__ __align__(16) __bf16 Bs[2][256 * 32];   // 16KB x2
  const int b = blockIdx.x;
  const int xcd = b & 7, loc = b >> 3;
  const int brow = (loc / 6) * 8 + xcd;          // 0..255
  const int inner = loc % 6;
  const int z = inner >> 1, bcol = inner & 1;
  const __bf16* W = (z == 0) ? Wqb : (z == 1) ? Wkb : Wvb;

  const int tid = threadIdx.x, wave = tid >> 6, lane = tid & 63;
  const int wr = wave >> 2, wn = wave & 3;       // 2 M-halves x 4 N-quarters
  const int lr = lane & 15, kq = lane >> 4;

  const __bf16* Abase = xb + (size_t)(brow * 256) * DIM;
  const __bf16* Bbase = W + (size_t)(bcol * 256) * DIM;

  // rows are 64B (32 bf16), 4 slots of 16B, swizzle slot ^= (row&3)
  auto stage = [&](int s, int kt) {
#pragma unroll
    for (int q = 0; q < 2; ++q) {
      const int L  = q * 8192 + tid * 16;
      const int r  = L >> 6;
      const int sl = (L >> 4) & 3;
      const int c  = ((sl ^ (r & 3)) << 3);
      load_lds16(Abase + (size_t)r * DIM + (kt + c),
                 (char*)As[s] + q * 8192 + wave * 1024);
      load_lds16(Bbase + (size_t)r * DIM + (kt + c),
                 (char*)Bs[s] + q * 8192 + wave * 1024);
    }
  };

  f32x4 acc[8][4] = {};
  stage(0, 0);
  __syncthreads();
  for (int t = 0; t < 16; ++t) {
    const int cur = t & 1;
    if (t < 15) stage(cur ^ 1, (t + 1) * 32);
    const char* Ac = (const char*)As[cur];
    const char* Bc = (const char*)Bs[cur];
    bf16x8 bfr[4], af[8];
#pragma unroll
    for (int j = 0; j < 4; ++j) {
      const int rB = wn * 64 + j * 16 + lr;
      bfr[j] = *reinterpret_cast<const bf16x8*>(Bc + rB * 64 + ((kq ^ (rB & 3)) << 4));
    }
#pragma unroll
    for (int i = 0; i < 8; ++i) {
      const int rA = wr * 128 + i * 16 + lr;
      af[i] = *reinterpret_cast<const bf16x8*>(Ac + rA * 64 + ((kq ^ (rA & 3)) << 4));
    }
#pragma unroll
    for (int i = 0; i < 8; ++i)
#pragma unroll
      for (int j = 0; j < 4; ++j)
        acc[i][j] = __builtin_amdgcn_mfma_f32_16x16x32_bf16(af[i], bfr[j], acc[i][j], 0, 0, 0);
    __syncthreads();
  }

  // epilogue
  const int m00 = brow * 256 + wr * 128 + kq * 4;
  const int n00 = bcol * 256 + wn * 64 + lr;
  if (z == 0) {
#pragma unroll
    for (int i = 0; i < 8; ++i)
#pragma unroll
      for (int j = 0; j < 4; ++j) {
        const int n = n00 + j * 16;
#pragma unroll
        for (int r = 0; r < 4; ++r) {
          const int m = m00 + i * 16 + r;
          float v = acc[i][j][r];
          v = (v > 0.f) ? (v + 1.f) : __expf(v);   // elu(v)+1
          Q[(size_t)m * DIM + n] = (__bf16)v;
        }
      }
  } else {
    __bf16* T = (z == 1) ? KT : VT;
    const int seq = (brow * 256) >> 11;
    float ks[4] = {0.f, 0.f, 0.f, 0.f};
#pragma unroll
    for (int i = 0; i < 8; ++i) {
      const int mb = m00 + i * 16;
      const int s0 = mb & 2047;
#pragma unroll
      for (int j = 0; j < 4; ++j) {
        const int d = n00 + j * 16;
        unsigned short h[4];
#pragma unroll
        for (int r = 0; r < 4; ++r) {
          float v = acc[i][j][r];
          if (z == 1) { v = (v > 0.f) ? (v + 1.f) : __expf(v); ks[j] += v; }
          h[r] = bfbits(v);
        }
        uint2 u;
        u.x = (uint32_t)h[0] | ((uint32_t)h[1] << 16);
        u.y = (uint32_t)h[2] | ((uint32_t)h[3] << 16);
        *reinterpret_cast<uint2*>(T + ((size_t)(seq * DIM + d) << 11) + s0) = u;
      }
    }
    if (z == 1) {
#pragma unroll
      for (int j = 0; j < 4; ++j) {
        float p = ks[j];
        p += __shfl_xor(p, 16, 64);
        p += __shfl_xor(p, 32, 64);
        if (kq == 0) atomicAdd(&ksum[seq * DIM + n00 + j * 16], p);
      }
    }
  }
}

// den[m] = max(sum_d Q[m,d]*ksum[seq,d], 1e-6); one wave per row (coalesced)
__global__ __launch_bounds__(256) void den_kernel(
    const __bf16* __restrict__ Q, const float* __restrict__ ksum,
    float* __restrict__ den)
{
  const int lane = threadIdx.x & 63;
  const int m = blockIdx.x * 4 + (threadIdx.x >> 6);
  bf16x8 qv = *reinterpret_cast<const bf16x8*>(Q + (size_t)m * DIM + lane * 8);
  const float* kp = ksum + ((m >> 11) << 9) + lane * 8;
  float s = 0.f;
#pragma unroll
  for (int t = 0; t < 8; ++t) s += (float)qv[t] * kp[t];
#pragma unroll
  for (int off = 32; off > 0; off >>= 1) s += __shfl_xor(s, off, 64);
  if (lane == 0) den[m] = fmaxf(s, 1e-6f);
}

// kvT[seq][e][d] = sum_s VT[seq][e][s] * KT[seq][d][s]; 512 blocks, XCD-pinned
__global__ __launch_bounds__(256) void kv_kernel(
    const __bf16* __restrict__ VT, const __bf16* __restrict__ KT,
    __bf16* __restrict__ kvT)
{
  __shared__ __align__(16) __bf16 Asm[128 * 64];
  __shared__ __align__(16) __bf16 Bsm[128 * 64];
  const int b = blockIdx.x;
  const int xcd = b & 7, loc = b >> 3;
  const int seq = (loc >> 4) * 8 + xcd;
  const int inner = loc & 15;
  const int bxx = inner >> 2, byy = inner & 3;
  const __bf16* A = VT + (size_t)seq * DIM * SLEN;
  const __bf16* B = KT + (size_t)seq * DIM * SLEN;
  f32x4 acc[4][4] = {};
  gemm_core(A, SLEN, bxx * 128, B, SLEN, byy * 128, SLEN, Asm, Bsm, acc);

  const int tid = threadIdx.x, wave = tid >> 6, lane = tid & 63;
  const int wr = wave >> 1, wc = wave & 1, lr = lane & 15, kq = lane >> 4;
  const int m0 = bxx * 128 + wr * 64 + kq * 4;
  const int n0 = byy * 128 + wc * 64 + lr;
  __bf16* C = kvT + (size_t)seq * DIM * DIM;
#pragma unroll
  for (int i = 0; i < 4; ++i)
#pragma unroll
    for (int j = 0; j < 4; ++j)
#pragma unroll
      for (int r = 0; r < 4; ++r)
        C[(size_t)(m0 + i * 16 + r) * DIM + (n0 + j * 16)] = (__bf16)acc[i][j][r];
}

// out[m,e] = (sum_d Q[m,d]*kvT[seq][e][d]) / den[m]; 2048 blocks, XCD-pinned
__global__ __launch_bounds__(256) void num_kernel(
    const __bf16* __restrict__ Q, const __bf16* __restrict__ kvT,
    const float* __restrict__ den, __bf16* __restrict__ out)
{
  __shared__ __align__(16) __bf16 Asm[128 * 64];
  __shared__ __align__(16) __bf16 Bsm[128 * 64];
  const int b = blockIdx.x;
  const int xcd = b & 7, loc = b >> 3;
  const int seq = (loc >> 6) * 8 + xcd;
  const int inner = loc & 63;
  const int brow = seq * 16 + (inner >> 2);
  const int bcol = inner & 3;
  f32x4 acc[4][4] = {};
  gemm_core(Q, DIM, brow * 128, kvT + (size_t)seq * DIM * DIM, DIM,
            bcol * 128, DIM, Asm, Bsm, acc);

  const int tid = threadIdx.x, wave = tid >> 6, lane = tid & 63;
  const int wr = wave >> 1, wc = wave & 1, lr = lane & 15, kq = lane >> 4;
  const int m0 = brow * 128 + wr * 64 + kq * 4;
  const int n0 = bcol * 128 + wc * 64 + lr;
  float rden[4][4];
#pragma unroll
  for (int i = 0; i < 4; ++i)
#pragma unroll
    for (int r = 0; r < 4; ++r)
      rden[i][r] = 1.f / den[m0 + i * 16 + r];
#pragma unroll
  for (int i = 0; i < 4; ++i)
#pragma unroll
    for (int j = 0; j < 4; ++j)
#pragma unroll
      for (int r = 0; r < 4; ++r)
        out[(size_t)(m0 + i * 16 + r) * DIM + (n0 + j * 16)] =
            (__bf16)(acc[i][j][r] * rden[i][r]);
}

// Fused out-proj + bias + residual + LayerNorm. 128 rows x 512 cols/block,
// 512 threads (8 waves 4x2). __launch_bounds__(512,1): acc[2][16]=128 f32 +
// temps ~190 VGPR, fits 2 waves/SIMD without spilling (round-2's default
// bounds chose 128 VGPR and spilled -> MfmaUtil 0.6%).
__global__ __launch_bounds__(512, 1) void final_kernel(
    const __bf16* __restrict__ outb, const __bf16* __restrict__ Wob,
    const float* __restrict__ bo, const float* __restrict__ gamma,
    const float* __restrict__ beta, float* __restrict__ y)
{
  __shared__ __align__(16) __bf16 Asm[128 * 32];   // 8KB
  __shared__ __align__(16) __bf16 Bsm[512 * 32];   // 32KB
  __shared__ float redS[2][128], redSS[2][128];
  const int tid = threadIdx.x, wave = tid >> 6, lane = tid & 63;
  const int Wr = wave >> 1, Wc = wave & 1;         // 4x2: 32 rows x 256 cols
  const int lr = lane & 15, kq = lane >> 4;
  const int brow = blockIdx.x;
  f32x4 acc[2][16] = {};

  for (int kt = 0; kt < DIM; kt += 32) {
    {
      const int L = tid * 16;                      // A: 8KB, one load/thread
      const int r = L >> 6, sl = (L >> 4) & 3;
      const int c = ((sl ^ (r & 3)) << 3);
      load_lds16(outb + (size_t)(brow * 128 + r) * DIM + (kt + c),
                 (char*)Asm + wave * 1024);
    }
#pragma unroll
    for (int q = 0; q < 4; ++q) {                  // B: 32KB, 4 loads/thread
      const int L = q * 8192 + tid * 16;
      const int r = L >> 6, sl = (L >> 4) & 3;
      const int c = ((sl ^ (r & 3)) << 3);
      load_lds16(Wob + (size_t)r * DIM + (kt + c),
                 (char*)Bsm + q * 8192 + wave * 1024);
    }
    __syncthreads();
    bf16x8 af[2];
#pragma unroll
    for (int i = 0; i < 2; ++i) {
      const int rA = Wr * 32 + i * 16 + lr;
      af[i] = *reinterpret_cast<const bf16x8*>(
          (char*)Asm + rA * 64 + ((kq ^ (rA & 3)) << 4));
    }
#pragma unroll
    for (int j = 0; j < 16; ++j) {
      const int rB = Wc * 256 + j * 16 + lr;
      bf16x8 bf = *reinterpret_cast<const bf16x8*>(
          (char*)Bsm + rB * 64 + ((kq ^ (rB & 3)) << 4));
#pragma unroll
      for (int i = 0; i < 2; ++i)
        acc[i][j] = __builtin_amdgcn_mfma_f32_16x16x32_bf16(af[i], bf, acc[i][j], 0, 0, 0);
    }
    __syncthreads();
  }

  // epilogue: v = acc + bo + residual; LN over 512 cols per row
  const int m0g = brow * 128;
  float sA[2][4] = {{0.f}}, ssA[2][4] = {{0.f}};
#pragma unroll
  for (int j = 0; j < 16; ++j) {
    const int n = Wc * 256 + j * 16 + lr;
    const float bon = bo[n];
#pragma unroll
    for (int i = 0; i < 2; ++i) {
      const int mb = m0g + Wr * 32 + i * 16 + kq * 4;
#pragma unroll
      for (int r = 0; r < 4; ++r) {
        float v = acc[i][j][r] + bon + (float)outb[(size_t)(mb + r) * DIM + n];
        acc[i][j][r] = v;
        sA[i][r] += v; ssA[i][r] += v * v;
      }
    }
  }
#pragma unroll
  for (int i = 0; i < 2; ++i)
#pragma unroll
    for (int r = 0; r < 4; ++r) {
      float s = sA[i][r], ss = ssA[i][r];
#pragma unroll
      for (int off = 1; off <= 8; off <<= 1) {
        s  += __shfl_xor(s,  off, 64);
        ss += __shfl_xor(ss, off, 64);
      }
      if (lr == 0) {
        const int ml = Wr * 32 + i * 16 + kq * 4 + r;
        redS[Wc][ml] = s; redSS[Wc][ml] = ss;
      }
    }
  __syncthreads();
  float mu_[2][4], rs_[2][4];
#pragma unroll
  for (int i = 0; i < 2; ++i)
#pragma unroll
    for (int r = 0; r < 4; ++r) {
      const int ml = Wr * 32 + i * 16 + kq * 4 + r;
      const float S  = redS[0][ml]  + redS[1][ml];
      const float SS = redSS[0][ml] + redSS[1][ml];
      const float mu = S * (1.f / 512.f);
      const float var = SS * (1.f / 512.f) - mu * mu;
      mu_[i][r] = mu;
      rs_[i][r] = rsqrtf(var + 1e-5f);
    }
#pragma unroll
  for (int j = 0; j < 16; ++j) {
    const int n = Wc * 256 + j * 16 + lr;
    const float g = gamma[n], bb = beta[n];
#pragma unroll
    for (int i = 0; i < 2; ++i) {
      const int mb = m0g + Wr * 32 + i * 16 + kq * 4;
#pragma unroll
      for (int r = 0; r < 4; ++r)
        y[(size_t)(mb + r) * DIM + n] = (acc[i][j][r] - mu_[i][r]) * rs_[i][r] * g + bb;
    }
  }
}

// ---------- launch ----------
extern "C" void kernel_launch(void* const* d_in, const int* in_sizes, int n_in,
                              void* d_out, int out_size, void* d_ws, size_t ws_size,
                              hipStream_t stream)
{
  const float* x     = (const float*)d_in[0];
  const float* Wq    = (const float*)d_in[1];
  const float* Wk    = (const float*)d_in[2];
  const float* Wv    = (const float*)d_in[3];
  const float* Wo    = (const float*)d_in[4];
  const float* bo    = (const float*)d_in[5];
  const float* gamma = (const float*)d_in[6];
  const float* beta  = (const float*)d_in[7];
  float* outp = (float*)d_out;

  char* ws = (char*)d_ws;
  const size_t SZ = 67108864;                      // 64 MiB (bf16 [65536][512])
  __bf16* xb   = (__bf16*)(ws + 0);                // reused as `out` after qkv
  __bf16* Q    = (__bf16*)(ws + SZ);
  __bf16* KT   = (__bf16*)(ws + 2 * SZ);
  __bf16* VT   = (__bf16*)(ws + 3 * SZ);
  __bf16* kvT  = (__bf16*)(ws + 4 * SZ);           // 16 MiB
  __bf16* Wqb  = (__bf16*)(ws + 4 * SZ + 16777216);
  __bf16* Wkb  = Wqb + 262144;
  __bf16* Wvb  = Wkb + 262144;
  __bf16* Wob  = Wvb + 262144;
  float*  ksum = (float*)(Wob + 262144);           // 64 KiB
  float*  den  = (float*)((char*)ksum + 65536);    // 256 KiB

  hipMemsetAsync(ksum, 0, SEQS * DIM * sizeof(float), stream);
  cast_kernel<<<4096, 256, 0, stream>>>(x, xb, MROWS * DIM / 8);
  cast4_kernel<<<dim3(128, 4), 256, 0, stream>>>(Wq, Wk, Wv, Wo, Wqb, Wkb, Wvb, Wob);

  qkv_kernel<<<1536, 512, 0, stream>>>(xb, Wqb, Wkb, Wvb, Q, KT, VT, ksum);
  den_kernel<<<16384, 256, 0, stream>>>(Q, ksum, den);
  kv_kernel<<<512, 256, 0, stream>>>(VT, KT, kvT);
  num_kernel<<<2048, 256, 0, stream>>>(Q, kvT, den, xb /*out*/);
  final_kernel<<<512, 512, 0, stream>>>(xb, Wob, bo, gamma, beta, outp);
}

// Round 5
// 420.963 us; speedup vs baseline: 1.1978x; 1.0072x over previous
//
#include <hip/hip_runtime.h>
#include <cstdint>

// ---------- types ----------
typedef __bf16 bf16x8 __attribute__((ext_vector_type(8)));
typedef float  f32x4  __attribute__((ext_vector_type(4)));

// Problem constants: BATCH=8, N_SEQS=4, SEQ_LEN=2048, D=512 -> 32 seqs, 65536 rows
#define SEQS   32
#define SLEN   2048
#define DIM    512
#define MROWS  65536

static __device__ __forceinline__ void load_lds16(const void* g, void* l) {
  __builtin_amdgcn_global_load_lds(
      (const __attribute__((address_space(1))) void*)(uintptr_t)g,
      (__attribute__((address_space(3))) void*)(uintptr_t)l,
      16, 0, 0);
}

static __device__ __forceinline__ unsigned short bfbits(float f) {
  __bf16 h = (__bf16)f;
  unsigned short u;
  __builtin_memcpy(&u, &h, 2);
  return u;
}

// ---------- BT-GEMM core, 128x128 tile, BK=64, 256 threads (4 waves 2x2) ----------
// 128B rows (full bank period), swizzle slot^(r&7): 0 conflicts (verified r2).
static __device__ __forceinline__ void gemm_core(
    const __bf16* __restrict__ A, int lda, int arow0,
    const __bf16* __restrict__ B, int ldb, int brow0,
    int K, __bf16* Asm, __bf16* Bsm, f32x4 (&acc)[4][4])
{
  const int tid  = threadIdx.x;
  const int wave = tid >> 6;
  const int lane = tid & 63;
  const int wr = wave >> 1, wc = wave & 1;
  const int lr = lane & 15, kq = lane >> 4;

  for (int kt = 0; kt < K; kt += 64) {
#pragma unroll
    for (int q = 0; q < 4; ++q) {
      const int L  = q * 4096 + tid * 16;
      const int r  = L >> 7;
      const int sl = (L >> 4) & 7;
      const int c  = ((sl ^ (r & 7)) << 3);
      load_lds16(A + (size_t)(arow0 + r) * lda + (kt + c),
                 (char*)Asm + q * 4096 + wave * 1024);
      load_lds16(B + (size_t)(brow0 + r) * ldb + (kt + c),
                 (char*)Bsm + q * 4096 + wave * 1024);
    }
    __syncthreads();

    bf16x8 af[2][4], bfr[2][4];
#pragma unroll
    for (int kk = 0; kk < 2; ++kk)
#pragma unroll
      for (int i = 0; i < 4; ++i) {
        const int rA = wr * 64 + i * 16 + lr;
        af[kk][i] = *reinterpret_cast<const bf16x8*>(
            (char*)Asm + rA * 128 + ((((kk * 4 + kq) ^ (rA & 7))) << 4));
        const int rB = wc * 64 + i * 16 + lr;
        bfr[kk][i] = *reinterpret_cast<const bf16x8*>(
            (char*)Bsm + rB * 128 + ((((kk * 4 + kq) ^ (rB & 7))) << 4));
      }
#pragma unroll
    for (int kk = 0; kk < 2; ++kk)
#pragma unroll
      for (int i = 0; i < 4; ++i)
#pragma unroll
        for (int j = 0; j < 4; ++j)
          acc[i][j] = __builtin_amdgcn_mfma_f32_16x16x32_bf16(
              af[kk][i], bfr[kk][j], acc[i][j], 0, 0, 0);
    __syncthreads();
  }
}

// ---------- kernels ----------

__global__ __launch_bounds__(256) void cast_kernel(
    const float* __restrict__ src, __bf16* __restrict__ dst, int n8)
{
  int i = blockIdx.x * blockDim.x + threadIdx.x;
  const int stride = gridDim.x * blockDim.x;
  for (; i < n8; i += stride) {
    const float4* p = reinterpret_cast<const float4*>(src + (size_t)i * 8);
    float4 a = p[0], b2 = p[1];
    float vals[8] = {a.x, a.y, a.z, a.w, b2.x, b2.y, b2.z, b2.w};
    uint32_t w[4];
#pragma unroll
    for (int t = 0; t < 4; ++t)
      w[t] = (uint32_t)bfbits(vals[2 * t]) | ((uint32_t)bfbits(vals[2 * t + 1]) << 16);
    uint4 o; o.x = w[0]; o.y = w[1]; o.z = w[2]; o.w = w[3];
    *reinterpret_cast<uint4*>(dst + (size_t)i * 8) = o;
  }
}

__global__ __launch_bounds__(256) void cast4_kernel(
    const float* __restrict__ a, const float* __restrict__ b,
    const float* __restrict__ c, const float* __restrict__ d,
    __bf16* __restrict__ ab, __bf16* __restrict__ bb,
    __bf16* __restrict__ cb, __bf16* __restrict__ db)
{
  const int z = blockIdx.y;
  const float* src = (z == 0) ? a : (z == 1) ? b : (z == 2) ? c : d;
  __bf16* dst = (z == 0) ? ab : (z == 1) ? bb : (z == 2) ? cb : db;
  const int i = blockIdx.x * 256 + threadIdx.x;
  const float4* p = reinterpret_cast<const float4*>(src + (size_t)i * 8);
  float4 x = p[0], y = p[1];
  float vals[8] = {x.x, x.y, x.z, x.w, y.x, y.y, y.z, y.w};
  uint32_t w[4];
#pragma unroll
  for (int t = 0; t < 4; ++t)
    w[t] = (uint32_t)bfbits(vals[2 * t]) | ((uint32_t)bfbits(vals[2 * t + 1]) << 16);
  uint4 o; o.x = w[0]; o.y = w[1]; o.z = w[2]; o.w = w[3];
  *reinterpret_cast<uint4*>(dst + (size_t)i * 8) = o;
}

// QKV projection: 256x256 tile, 512 threads (8 waves 2Mx4N), BK=32,
// double-buffered LDS (64KB), one barrier per K-tile.
// BK=32 -> 64B rows = HALF the 128B bank period, so rows r and r+2 share a
// bank start. Swizzle must be slot ^= ((r>>1)&3): 8 same-parity rows spread
// over 4 slots -> 2-way (free). Round-4's (r&3) gave {0,2} only -> 4-way,
// 9.4e6 conflicts. Same involution applied at stage (global src col) and read.
__global__ __launch_bounds__(512, 1) void qkv_kernel(
    const __bf16* __restrict__ xb,
    const __bf16* __restrict__ Wqb, const __bf16* __restrict__ Wkb,
    const __bf16* __restrict__ Wvb,
    __bf16* __restrict__ Q, __bf16* __restrict__ KT, __bf16* __restrict__ VT,
    float* __restrict__ ksum)
{
  __shared__ __align__(16) __bf16 As[2][256 * 32];   // 16KB x2
  __shared__ __align__(16) __bf16 Bs[2][256 * 32];   // 16KB x2
  const int b = blockIdx.x;
  const int xcd = b & 7, loc = b >> 3;
  const int brow = (loc / 6) * 8 + xcd;          // 0..255
  const int inner = loc % 6;
  const int z = inner >> 1, bcol = inner & 1;
  const __bf16* W = (z == 0) ? Wqb : (z == 1) ? Wkb : Wvb;

  const int tid = threadIdx.x, wave = tid >> 6, lane = tid & 63;
  const int wr = wave >> 2, wn = wave & 3;       // 2 M-halves x 4 N-quarters
  const int lr = lane & 15, kq = lane >> 4;

  const __bf16* Abase = xb + (size_t)(brow * 256) * DIM;
  const __bf16* Bbase = W + (size_t)(bcol * 256) * DIM;

  // rows are 64B (32 bf16), 4 slots of 16B, swizzle slot ^= ((row>>1)&3)
  auto stage = [&](int s, int kt) {
#pragma unroll
    for (int q = 0; q < 2; ++q) {
      const int L  = q * 8192 + tid * 16;
      const int r  = L >> 6;
      const int sl = (L >> 4) & 3;
      const int c  = ((sl ^ ((r >> 1) & 3)) << 3);
      load_lds16(Abase + (size_t)r * DIM + (kt + c),
                 (char*)As[s] + q * 8192 + wave * 1024);
      load_lds16(Bbase + (size_t)r * DIM + (kt + c),
                 (char*)Bs[s] + q * 8192 + wave * 1024);
    }
  };

  f32x4 acc[8][4] = {};
  stage(0, 0);
  __syncthreads();
  for (int t = 0; t < 16; ++t) {
    const int cur = t & 1;
    if (t < 15) stage(cur ^ 1, (t + 1) * 32);
    const char* Ac = (const char*)As[cur];
    const char* Bc = (const char*)Bs[cur];
    bf16x8 bfr[4], af[8];
#pragma unroll
    for (int j = 0; j < 4; ++j) {
      const int rB = wn * 64 + j * 16 + lr;
      bfr[j] = *reinterpret_cast<const bf16x8*>(
          Bc + rB * 64 + ((kq ^ ((rB >> 1) & 3)) << 4));
    }
#pragma unroll
    for (int i = 0; i < 8; ++i) {
      const int rA = wr * 128 + i * 16 + lr;
      af[i] = *reinterpret_cast<const bf16x8*>(
          Ac + rA * 64 + ((kq ^ ((rA >> 1) & 3)) << 4));
    }
#pragma unroll
    for (int i = 0; i < 8; ++i)
#pragma unroll
      for (int j = 0; j < 4; ++j)
        acc[i][j] = __builtin_amdgcn_mfma_f32_16x16x32_bf16(af[i], bfr[j], acc[i][j], 0, 0, 0);
    __syncthreads();
  }

  // epilogue
  const int m00 = brow * 256 + wr * 128 + kq * 4;
  const int n00 = bcol * 256 + wn * 64 + lr;
  if (z == 0) {
#pragma unroll
    for (int i = 0; i < 8; ++i)
#pragma unroll
      for (int j = 0; j < 4; ++j) {
        const int n = n00 + j * 16;
#pragma unroll
        for (int r = 0; r < 4; ++r) {
          const int m = m00 + i * 16 + r;
          float v = acc[i][j][r];
          v = (v > 0.f) ? (v + 1.f) : __expf(v);   // elu(v)+1
          Q[(size_t)m * DIM + n] = (__bf16)v;
        }
      }
  } else {
    __bf16* T = (z == 1) ? KT : VT;
    const int seq = (brow * 256) >> 11;
    float ks[4] = {0.f, 0.f, 0.f, 0.f};
#pragma unroll
    for (int i = 0; i < 8; ++i) {
      const int mb = m00 + i * 16;
      const int s0 = mb & 2047;
#pragma unroll
      for (int j = 0; j < 4; ++j) {
        const int d = n00 + j * 16;
        unsigned short h[4];
#pragma unroll
        for (int r = 0; r < 4; ++r) {
          float v = acc[i][j][r];
          if (z == 1) { v = (v > 0.f) ? (v + 1.f) : __expf(v); ks[j] += v; }
          h[r] = bfbits(v);
        }
        uint2 u;
        u.x = (uint32_t)h[0] | ((uint32_t)h[1] << 16);
        u.y = (uint32_t)h[2] | ((uint32_t)h[3] << 16);
        *reinterpret_cast<uint2*>(T + ((size_t)(seq * DIM + d) << 11) + s0) = u;
      }
    }
    if (z == 1) {
#pragma unroll
      for (int j = 0; j < 4; ++j) {
        float p = ks[j];
        p += __shfl_xor(p, 16, 64);
        p += __shfl_xor(p, 32, 64);
        if (kq == 0) atomicAdd(&ksum[seq * DIM + n00 + j * 16], p);
      }
    }
  }
}

// den[m] = max(sum_d Q[m,d]*ksum[seq,d], 1e-6); one wave per row (coalesced)
__global__ __launch_bounds__(256) void den_kernel(
    const __bf16* __restrict__ Q, const float* __restrict__ ksum,
    float* __restrict__ den)
{
  const int lane = threadIdx.x & 63;
  const int m = blockIdx.x * 4 + (threadIdx.x >> 6);
  bf16x8 qv = *reinterpret_cast<const bf16x8*>(Q + (size_t)m * DIM + lane * 8);
  const float* kp = ksum + ((m >> 11) << 9) + lane * 8;
  float s = 0.f;
#pragma unroll
  for (int t = 0; t < 8; ++t) s += (float)qv[t] * kp[t];
#pragma unroll
  for (int off = 32; off > 0; off >>= 1) s += __shfl_xor(s, off, 64);
  if (lane == 0) den[m] = fmaxf(s, 1e-6f);
}

// kvT[seq][e][d] = sum_s VT[seq][e][s] * KT[seq][d][s]; 512 blocks, XCD-pinned
__global__ __launch_bounds__(256) void kv_kernel(
    const __bf16* __restrict__ VT, const __bf16* __restrict__ KT,
    __bf16* __restrict__ kvT)
{
  __shared__ __align__(16) __bf16 Asm[128 * 64];
  __shared__ __align__(16) __bf16 Bsm[128 * 64];
  const int b = blockIdx.x;
  const int xcd = b & 7, loc = b >> 3;
  const int seq = (loc >> 4) * 8 + xcd;
  const int inner = loc & 15;
  const int bxx = inner >> 2, byy = inner & 3;
  const __bf16* A = VT + (size_t)seq * DIM * SLEN;
  const __bf16* B = KT + (size_t)seq * DIM * SLEN;
  f32x4 acc[4][4] = {};
  gemm_core(A, SLEN, bxx * 128, B, SLEN, byy * 128, SLEN, Asm, Bsm, acc);

  const int tid = threadIdx.x, wave = tid >> 6, lane = tid & 63;
  const int wr = wave >> 1, wc = wave & 1, lr = lane & 15, kq = lane >> 4;
  const int m0 = bxx * 128 + wr * 64 + kq * 4;
  const int n0 = byy * 128 + wc * 64 + lr;
  __bf16* C = kvT + (size_t)seq * DIM * DIM;
#pragma unroll
  for (int i = 0; i < 4; ++i)
#pragma unroll
    for (int j = 0; j < 4; ++j)
#pragma unroll
      for (int r = 0; r < 4; ++r)
        C[(size_t)(m0 + i * 16 + r) * DIM + (n0 + j * 16)] = (__bf16)acc[i][j][r];
}

// out[m,e] = (sum_d Q[m,d]*kvT[seq][e][d]) / den[m]; 2048 blocks, XCD-pinned
__global__ __launch_bounds__(256) void num_kernel(
    const __bf16* __restrict__ Q, const __bf16* __restrict__ kvT,
    const float* __restrict__ den, __bf16* __restrict__ out)
{
  __shared__ __align__(16) __bf16 Asm[128 * 64];
  __shared__ __align__(16) __bf16 Bsm[128 * 64];
  const int b = blockIdx.x;
  const int xcd = b & 7, loc = b >> 3;
  const int seq = (loc >> 6) * 8 + xcd;
  const int inner = loc & 63;
  const int brow = seq * 16 + (inner >> 2);
  const int bcol = inner & 3;
  f32x4 acc[4][4] = {};
  gemm_core(Q, DIM, brow * 128, kvT + (size_t)seq * DIM * DIM, DIM,
            bcol * 128, DIM, Asm, Bsm, acc);

  const int tid = threadIdx.x, wave = tid >> 6, lane = tid & 63;
  const int wr = wave >> 1, wc = wave & 1, lr = lane & 15, kq = lane >> 4;
  const int m0 = brow * 128 + wr * 64 + kq * 4;
  const int n0 = bcol * 128 + wc * 64 + lr;
  float rden[4][4];
#pragma unroll
  for (int i = 0; i < 4; ++i)
#pragma unroll
    for (int r = 0; r < 4; ++r)
      rden[i][r] = 1.f / den[m0 + i * 16 + r];
#pragma unroll
  for (int i = 0; i < 4; ++i)
#pragma unroll
    for (int j = 0; j < 4; ++j)
#pragma unroll
      for (int r = 0; r < 4; ++r)
        out[(size_t)(m0 + i * 16 + r) * DIM + (n0 + j * 16)] =
            (__bf16)(acc[i][j][r] * rden[i][r]);
}

// Fused out-proj + bias + residual + LayerNorm. 128 rows x 512 cols/block,
// 512 threads (8 waves 4x2), __launch_bounds__(512,1) (acc[2][16]=128 f32,
// needs ~190 VGPR -> 2 waves/SIMD). 64B rows -> swizzle slot ^= ((r>>1)&3)
// (same fix as qkv; (r&3) was a 4-way conflict).
__global__ __launch_bounds__(512, 1) void final_kernel(
    const __bf16* __restrict__ outb, const __bf16* __restrict__ Wob,
    const float* __restrict__ bo, const float* __restrict__ gamma,
    const float* __restrict__ beta, float* __restrict__ y)
{
  __shared__ __align__(16) __bf16 Asm[128 * 32];   // 8KB
  __shared__ __align__(16) __bf16 Bsm[512 * 32];   // 32KB
  __shared__ float redS[2][128], redSS[2][128];
  const int tid = threadIdx.x, wave = tid >> 6, lane = tid & 63;
  const int Wr = wave >> 1, Wc = wave & 1;         // 4x2: 32 rows x 256 cols
  const int lr = lane & 15, kq = lane >> 4;
  const int brow = blockIdx.x;
  f32x4 acc[2][16] = {};

  for (int kt = 0; kt < DIM; kt += 32) {
    {
      const int L = tid * 16;                      // A: 8KB, one load/thread
      const int r = L >> 6, sl = (L >> 4) & 3;
      const int c = ((sl ^ ((r >> 1) & 3)) << 3);
      load_lds16(outb + (size_t)(brow * 128 + r) * DIM + (kt + c),
                 (char*)Asm + wave * 1024);
    }
#pragma unroll
    for (int q = 0; q < 4; ++q) {                  // B: 32KB, 4 loads/thread
      const int L = q * 8192 + tid * 16;
      const int r = L >> 6, sl = (L >> 4) & 3;
      const int c = ((sl ^ ((r >> 1) & 3)) << 3);
      load_lds16(Wob + (size_t)r * DIM + (kt + c),
                 (char*)Bsm + q * 8192 + wave * 1024);
    }
    __syncthreads();
    bf16x8 af[2];
#pragma unroll
    for (int i = 0; i < 2; ++i) {
      const int rA = Wr * 32 + i * 16 + lr;
      af[i] = *reinterpret_cast<const bf16x8*>(
          (char*)Asm + rA * 64 + ((kq ^ ((rA >> 1) & 3)) << 4));
    }
#pragma unroll
    for (int j = 0; j < 16; ++j) {
      const int rB = Wc * 256 + j * 16 + lr;
      bf16x8 bf = *reinterpret_cast<const bf16x8*>(
          (char*)Bsm + rB * 64 + ((kq ^ ((rB >> 1) & 3)) << 4));
#pragma unroll
      for (int i = 0; i < 2; ++i)
        acc[i][j] = __builtin_amdgcn_mfma_f32_16x16x32_bf16(af[i], bf, acc[i][j], 0, 0, 0);
    }
    __syncthreads();
  }

  // epilogue: v = acc + bo + residual; LN over 512 cols per row
  const int m0g = brow * 128;
  float sA[2][4] = {{0.f}}, ssA[2][4] = {{0.f}};
#pragma unroll
  for (int j = 0; j < 16; ++j) {
    const int n = Wc * 256 + j * 16 + lr;
    const float bon = bo[n];
#pragma unroll
    for (int i = 0; i < 2; ++i) {
      const int mb = m0g + Wr * 32 + i * 16 + kq * 4;
#pragma unroll
      for (int r = 0; r < 4; ++r) {
        float v = acc[i][j][r] + bon + (float)outb[(size_t)(mb + r) * DIM + n];
        acc[i][j][r] = v;
        sA[i][r] += v; ssA[i][r] += v * v;
      }
    }
  }
#pragma unroll
  for (int i = 0; i < 2; ++i)
#pragma unroll
    for (int r = 0; r < 4; ++r) {
      float s = sA[i][r], ss = ssA[i][r];
#pragma unroll
      for (int off = 1; off <= 8; off <<= 1) {
        s  += __shfl_xor(s,  off, 64);
        ss += __shfl_xor(ss, off, 64);
      }
      if (lr == 0) {
        const int ml = Wr * 32 + i * 16 + kq * 4 + r;
        redS[Wc][ml] = s; redSS[Wc][ml] = ss;
      }
    }
  __syncthreads();
  float mu_[2][4], rs_[2][4];
#pragma unroll
  for (int i = 0; i < 2; ++i)
#pragma unroll
    for (int r = 0; r < 4; ++r) {
      const int ml = Wr * 32 + i * 16 + kq * 4 + r;
      const float S  = redS[0][ml]  + redS[1][ml];
      const float SS = redSS[0][ml] + redSS[1][ml];
      const float mu = S * (1.f / 512.f);
      const float var = SS * (1.f / 512.f) - mu * mu;
      mu_[i][r] = mu;
      rs_[i][r] = rsqrtf(var + 1e-5f);
    }
#pragma unroll
  for (int j = 0; j < 16; ++j) {
    const int n = Wc * 256 + j * 16 + lr;
    const float g = gamma[n], bb = beta[n];
#pragma unroll
    for (int i = 0; i < 2; ++i) {
      const int mb = m0g + Wr * 32 + i * 16 + kq * 4;
#pragma unroll
      for (int r = 0; r < 4; ++r)
        y[(size_t)(mb + r) * DIM + n] = (acc[i][j][r] - mu_[i][r]) * rs_[i][r] * g + bb;
    }
  }
}

// ---------- launch ----------
extern "C" void kernel_launch(void* const* d_in, const int* in_sizes, int n_in,
                              void* d_out, int out_size, void* d_ws, size_t ws_size,
                              hipStream_t stream)
{
  const float* x     = (const float*)d_in[0];
  const float* Wq    = (const float*)d_in[1];
  const float* Wk    = (const float*)d_in[2];
  const float* Wv    = (const float*)d_in[3];
  const float* Wo    = (const float*)d_in[4];
  const float* bo    = (const float*)d_in[5];
  const float* gamma = (const float*)d_in[6];
  const float* beta  = (const float*)d_in[7];
  float* outp = (float*)d_out;

  char* ws = (char*)d_ws;
  const size_t SZ = 67108864;                      // 64 MiB (bf16 [65536][512])
  __bf16* xb   = (__bf16*)(ws + 0);                // reused as `out` after qkv
  __bf16* Q    = (__bf16*)(ws + SZ);
  __bf16* KT   = (__bf16*)(ws + 2 * SZ);
  __bf16* VT   = (__bf16*)(ws + 3 * SZ);
  __bf16* kvT  = (__bf16*)(ws + 4 * SZ);           // 16 MiB
  __bf16* Wqb  = (__bf16*)(ws + 4 * SZ + 16777216);
  __bf16* Wkb  = Wqb + 262144;
  __bf16* Wvb  = Wkb + 262144;
  __bf16* Wob  = Wvb + 262144;
  float*  ksum = (float*)(Wob + 262144);           // 64 KiB
  float*  den  = (float*)((char*)ksum + 65536);    // 256 KiB

  hipMemsetAsync(ksum, 0, SEQS * DIM * sizeof(float), stream);
  cast_kernel<<<4096, 256, 0, stream>>>(x, xb, MROWS * DIM / 8);
  cast4_kernel<<<dim3(128, 4), 256, 0, stream>>>(Wq, Wk, Wv, Wo, Wqb, Wkb, Wvb, Wob);

  qkv_kernel<<<1536, 512, 0, stream>>>(xb, Wqb, Wkb, Wvb, Q, KT, VT, ksum);
  den_kernel<<<16384, 256, 0, stream>>>(Q, ksum, den);
  kv_kernel<<<512, 256, 0, stream>>>(VT, KT, kvT);
  num_kernel<<<2048, 256, 0, stream>>>(Q, kvT, den, xb /*out*/);
  final_kernel<<<512, 512, 0, stream>>>(xb, Wob, bo, gamma, beta, outp);
}